// Round 9
// baseline (671.943 us; speedup 1.0000x reference)
//
#include <hip/hip_runtime.h>
#include <hip/hip_bf16.h>

// ---------------------------------------------------------------------------
// Decoder layer: SA(causal)+LN, CA+LN, FFN+LN.  B=2,S=2048,D=1024,H=16,DH=64,F=4096
// bf16 MFMA GEMMs (BK=64, XOR-swizzled LDS, global_load_lds, split-K) +
// split-K flash attention on 32x32x16 MFMA (S^T orient, fixed-max softmax,
// shfl-based P transform, flash-decoding combine).
// ---------------------------------------------------------------------------

typedef __attribute__((ext_vector_type(8))) short bf16x8;
typedef __attribute__((ext_vector_type(4))) float f32x4;
typedef __attribute__((ext_vector_type(16))) float f32x16;

#define LOG2E 1.44269504088896340736f

constexpr int Bb = 2, Ss = 2048, Dd = 1024, Hh = 16, DHd = 64, Ff = 4096;
constexpr int Mrows = Bb * Ss;  // 4096
constexpr int BHS = Bb * Hh * Ss;  // 65536 queries

static __device__ __forceinline__ ushort f2b(float f) {
    union { float f; unsigned u; } x{f};
    unsigned r = x.u + 0x7fffu + ((x.u >> 16) & 1u);  // RNE
    return (ushort)(r >> 16);
}

// pack 2 fp32 -> 2 bf16, RNE (library)
static __device__ __forceinline__ unsigned pk2(float a, float b) {
    __hip_bfloat162 h = __float22bfloat162_rn(make_float2(a, b));
    unsigned u;
    __builtin_memcpy(&u, &h, 4);
    return u;
}

// pack 2 fp32 -> 2 bf16 by TRUNCATION: single v_perm_b32.
static __device__ __forceinline__ unsigned pk2t(float a, float b) {
    union { float f; unsigned u; } ua{a}, ub{b};
    return __builtin_amdgcn_perm(ub.u, ua.u, 0x07060302);
}

// async global->LDS, 16B per lane (wave-uniform LDS base + lane*16)
static __device__ __forceinline__ void gl2lds16(const void* g, void* l) {
    __builtin_amdgcn_global_load_lds(
        (const __attribute__((address_space(1))) void*)g,
        (__attribute__((address_space(3))) void*)l, 16, 0, 0);
}

// ---------------------------------------------------------------------------
__global__ __launch_bounds__(256) void cvt_kernel(const float* __restrict__ in,
                                                  ushort* __restrict__ out) {
    int i = (blockIdx.x * 256 + threadIdx.x) * 4;
    float4 v = *(const float4*)(in + i);
    ushort4 u;
    u.x = f2b(v.x); u.y = f2b(v.y); u.z = f2b(v.z); u.w = f2b(v.w);
    *(ushort4*)(out + i) = u;
}

// weight (K,N) fp32 -> (N,K) bf16 transpose.  grid (N/32, K/32), block 256
__global__ __launch_bounds__(256) void wtrans_kernel(const float* __restrict__ w,
                                                     ushort* __restrict__ wT,
                                                     int K, int N) {
    __shared__ float t[32][33];
    int tx = threadIdx.x & 31, ty = threadIdx.x >> 5;
    int kb = blockIdx.y * 32, nb = blockIdx.x * 32;
#pragma unroll
    for (int i = 0; i < 4; i++)
        t[ty + i * 8][tx] = w[(size_t)(kb + ty + i * 8) * N + nb + tx];
    __syncthreads();
#pragma unroll
    for (int i = 0; i < 4; i++)
        wT[(size_t)(nb + ty + i * 8) * K + kb + tx] = f2b(t[tx][ty + i * 8]);
}

__global__ __launch_bounds__(256) void pack_bias(const float* __restrict__ a,
                                                 const float* __restrict__ b,
                                                 const float* __restrict__ c,
                                                 float* __restrict__ out) {
    int i = blockIdx.x * 256 + threadIdx.x;
    const float* src = a; int j = i;
    if (i >= 2048)      { src = c; j = i - 2048; }
    else if (i >= 1024) { src = b; j = i - 1024; }
    out[i] = src[j];
}

// ---------------------------------------------------------------------------
// GEMM: C[M,N] = A[M,K](bf16,row) @ BT[N,K](bf16,row)^T + bias
// BK=64 K-loop, global_load_lds(16B) into [128][64] tiles with XOR chunk
// swizzle; reads use slot = (kk*4+quad) ^ (lr&7) -> conflict-free.
// Split-K: blockIdx.z handles [z*klen,(z+1)*klen); mode 0 writes fp32 partial
// to out + z*M*N; bias only added by z==0.
__global__ __launch_bounds__(256) void gemm_kernel(const ushort* __restrict__ A,
                                                   const ushort* __restrict__ BT,
                                                   const float* __restrict__ bias,
                                                   void* __restrict__ out,
                                                   int M, int N, int K, int klen,
                                                   int mode, int relu, float qsc,
                                                   int vwhich) {
    __shared__ __align__(16) ushort As[128 * 64];
    __shared__ __align__(16) ushort Bs[128 * 64];
    const int tid = threadIdx.x;
    const int lane = tid & 63, wave = tid >> 6;
    const int lr = lane & 15, quad = lane >> 4;
    const int wm = wave & 1, wn = wave >> 1;
    const int m0 = blockIdx.y * 128, n0 = blockIdx.x * 128;
    const int kz = blockIdx.z;
    const int kstart = kz * klen;

    f32x4 acc[4][4];
#pragma unroll
    for (int i = 0; i < 4; i++)
#pragma unroll
        for (int j = 0; j < 4; j++) acc[i][j] = (f32x4){0.f, 0.f, 0.f, 0.f};

    const int srow = tid >> 3;
    const int gchunk = ((tid & 7) ^ (srow & 7)) * 8;
    const ushort* aBase = A + (size_t)(m0 + srow) * K + gchunk;
    const ushort* bBase = BT + (size_t)(n0 + srow) * K + gchunk;
    const size_t rowStep = (size_t)32 * K;

    const int slotA = ((quad) ^ (lr & 7)) * 8;
    const int slotB = ((4 + quad) ^ (lr & 7)) * 8;

    for (int k0 = kstart; k0 < kstart + klen; k0 += 64) {
#pragma unroll
        for (int c = 0; c < 4; c++) {
            gl2lds16(aBase + c * rowStep + k0, &As[c * 2048 + tid * 8]);
            gl2lds16(bBase + c * rowStep + k0, &Bs[c * 2048 + tid * 8]);
        }
        __syncthreads();
#pragma unroll
        for (int kk = 0; kk < 2; kk++) {
            const int slot = kk ? slotB : slotA;
            bf16x8 af[4], bfr[4];
#pragma unroll
            for (int i = 0; i < 4; i++)
                af[i] = *(const bf16x8*)&As[(wm * 64 + i * 16 + lr) * 64 + slot];
#pragma unroll
            for (int j = 0; j < 4; j++)
                bfr[j] = *(const bf16x8*)&Bs[(wn * 64 + j * 16 + lr) * 64 + slot];
#pragma unroll
            for (int i = 0; i < 4; i++)
#pragma unroll
                for (int j = 0; j < 4; j++)
                    acc[i][j] = __builtin_amdgcn_mfma_f32_16x16x32_bf16(af[i], bfr[j], acc[i][j], 0, 0, 0);
        }
        __syncthreads();
    }

#pragma unroll
    for (int j = 0; j < 4; j++) {
        int col = n0 + wn * 64 + j * 16 + lr;
        float bv = (bias && kz == 0) ? bias[col] : 0.f;
#pragma unroll
        for (int i = 0; i < 4; i++) {
            int row0 = m0 + wm * 64 + i * 16 + quad * 4;
            float v[4];
#pragma unroll
            for (int r = 0; r < 4; r++) {
                v[r] = acc[i][j][r] + bv;
                if (relu) v[r] = fmaxf(v[r], 0.f);
            }
            if (mode == 0) {
                float* op = (float*)out + (size_t)kz * M * N;
#pragma unroll
                for (int r = 0; r < 4; r++)
                    op[(size_t)(row0 + r) * N + col] = v[r];
            } else if (mode == 1) {
#pragma unroll
                for (int r = 0; r < 4; r++)
                    ((ushort*)out)[(size_t)(row0 + r) * N + col] = f2b(v[r]);
            } else {
                int which = col >> 10, n1 = col & 1023;
                int h = n1 >> 6, dh = n1 & 63;
                int b = row0 >> 11, s0 = row0 & 2047;
                size_t wbase = (size_t)which * (Bb * Hh * Ss * DHd);
                if (which == vwhich) {  // V: write transposed (b,h,dh,s)
                    uint2 pk;
                    pk.x = pk2(v[0], v[1]); pk.y = pk2(v[2], v[3]);
                    *(uint2*)((ushort*)out + wbase +
                              ((size_t)(b * Hh + h) * DHd + dh) * Ss + s0) = pk;
                } else {
                    float sc = (which == 0) ? qsc : 1.f;
#pragma unroll
                    for (int r = 0; r < 4; r++)
                        ((ushort*)out)[wbase + (((size_t)(b * Hh + h) * Ss + s0 + r) * DHd) + dh] =
                            f2b(v[r] * sc);
                }
            }
        }
    }
}

// ---------------------------------------------------------------------------
// Split-K flash attention on 32x32x16 MFMA.  Wave owns 32 queries (block =
// 128).  S^T = K·Q^T; fixed-max softmax (clamp 88); O^T = V^T·P^T with P
// moved C-layout -> B-layout via in-lane repack + shfl_xor(32) (no LDS).
// blockIdx.z = split p (2, interleaved kt ≡ p mod 2).  Q pre-scaled.
// Layouts (32x32x16 bf16): A[m][k]: m=lane&31, k=8*(lane>>5)+j.
// C/D: col=lane&31, row=(reg&3)+8*(reg>>2)+4*(lane>>5).
__global__ __launch_bounds__(256, 4) void attn_kernel(const ushort* __restrict__ Q,
                                                      const ushort* __restrict__ Kg,
                                                      const ushort* __restrict__ VT,
                                                      float* __restrict__ Op0,
                                                      float* __restrict__ Op1,
                                                      float* __restrict__ Ml,
                                                      int causal) {
    __shared__ ushort Ks[64][72];      // (key, d)
    __shared__ ushort Vs[64][72];      // (d, key)
    const int tid = threadIdx.x;
    const int lane = tid & 63, w = tid >> 6;
    const int l31 = lane & 31, h = lane >> 5;
    const int p = blockIdx.z;
    const int qt = causal ? (gridDim.x - 1 - blockIdx.x) : blockIdx.x;
    const int bh = blockIdx.y;
    const size_t hb = (size_t)bh * Ss * DHd;
    const int qrow = qt * 128 + w * 32;
    const int qg = qrow + l31;

    // Q fragments (B-operand): lane holds Q[qg][m*16 + h*8 + j]
    bf16x8 qf[4];
#pragma unroll
    for (int m = 0; m < 4; m++)
        qf[m] = *(const bf16x8*)(Q + hb + (size_t)qg * DHd + m * 16 + h * 8);

    f32x16 o[2];
#pragma unroll
    for (int dt = 0; dt < 2; dt++)
#pragma unroll
        for (int r = 0; r < 16; r++) o[dt][r] = 0.f;
    float l_i = 0.f;

    const int srow = tid >> 3, sseg = tid & 7;

    const int ktEnd = causal ? (2 * qt + 2) : (Ss / 64);
    for (int kt = p; kt < ktEnd; kt += 2) {
        const int k0 = kt * 64;
#pragma unroll
        for (int io = 0; io < 2; io++) {
            *(bf16x8*)&Ks[srow + io * 32][sseg * 8] =
                *(const bf16x8*)(Kg + hb + (size_t)(k0 + srow + io * 32) * DHd + sseg * 8);
            *(bf16x8*)&Vs[srow + io * 32][sseg * 8] =
                *(const bf16x8*)(VT + hb + (size_t)(srow + io * 32) * Ss + k0 + sseg * 8);
        }
        __syncthreads();

        float psum = 0.f;
        unsigned P[2][8];   // packed P dwords per kh tile (regs 2i, 2i+1)
#pragma unroll
        for (int kh = 0; kh < 2; kh++) {
            // S^T tile (64 keys half kh x 32 queries)
            f32x16 st;
#pragma unroll
            for (int r = 0; r < 16; r++) st[r] = 0.f;
#pragma unroll
            for (int m = 0; m < 4; m++) {
                bf16x8 a = *(const bf16x8*)&Ks[kh * 32 + l31][m * 16 + h * 8];
                st = __builtin_amdgcn_mfma_f32_32x32x16_bf16(a, qf[m], st, 0, 0, 0);
            }
            if (causal && kt >= 2 * qt) {
#pragma unroll
                for (int r = 0; r < 16; r++) {
                    int key = k0 + kh * 32 + (r & 3) + 8 * (r >> 2) + 4 * h;
                    if (key > qg) st[r] = -1e30f;
                }
            }
            // fixed-max softmax
            float pv[16];
#pragma unroll
            for (int r = 0; r < 16; r++) {
                pv[r] = __builtin_amdgcn_exp2f(fminf(st[r], 88.f));
                psum += pv[r];
            }
#pragma unroll
            for (int i = 0; i < 8; i++) P[kh][i] = pk2t(pv[2 * i], pv[2 * i + 1]);
        }
        psum += __shfl_xor(psum, 32);
        l_i += psum;

        // P (C-layout) -> B-operand frags via shfl_xor(32)
        bf16x8 bfrag[4];
#pragma unroll
        for (int kh = 0; kh < 2; kh++)
#pragma unroll
            for (int mm = 0; mm < 2; mm++) {
                int sbase = 2 * (2 * mm + 1 - h);   // pack idx of send group
                unsigned s0 = P[kh][sbase], s1 = P[kh][sbase + 1];
                unsigned r0 = __shfl_xor(s0, 32), r1 = __shfl_xor(s1, 32);
                int lbase = 4 * mm + 2 * h;         // pack idx of local group
                union { unsigned u[4]; bf16x8 v; } bu;
                if (h == 0) {
                    bu.u[0] = P[kh][lbase]; bu.u[1] = P[kh][lbase + 1];
                    bu.u[2] = r0;           bu.u[3] = r1;
                } else {
                    bu.u[0] = r0;           bu.u[1] = r1;
                    bu.u[2] = P[kh][lbase]; bu.u[3] = P[kh][lbase + 1];
                }
                bfrag[kh * 2 + mm] = bu.v;
            }
        // O^T += V^T·P^T
#pragma unroll
        for (int dt = 0; dt < 2; dt++)
#pragma unroll
            for (int m = 0; m < 4; m++) {
                bf16x8 a = *(const bf16x8*)&Vs[dt * 32 + l31][m * 16 + h * 8];
                o[dt] = __builtin_amdgcn_mfma_f32_32x32x16_bf16(a, bfrag[m], o[dt], 0, 0, 0);
            }
        __syncthreads();
    }

    // write partials (unnormalized O + l)
    float* Op = p ? Op1 : Op0;
    if (h == 0)
        Ml[(size_t)p * BHS + (size_t)bh * Ss + qg] = l_i;
    size_t ob = ((size_t)bh * Ss + qg) * 64;
#pragma unroll
    for (int dt = 0; dt < 2; dt++)
#pragma unroll
        for (int g = 0; g < 4; g++) {
            f32x4 v = {o[dt][4 * g], o[dt][4 * g + 1], o[dt][4 * g + 2], o[dt][4 * g + 3]};
            *(f32x4*)(Op + ob + dt * 32 + g * 8 + 4 * h) = v;
        }
}

// ---------------------------------------------------------------------------
// combine 2 split partials -> O (B*S, D) bf16.  16 threads per query (4 d each)
__global__ __launch_bounds__(256) void attn_combine(const float* __restrict__ Op0,
                                                    const float* __restrict__ Op1,
                                                    const float* __restrict__ Ml,
                                                    ushort* __restrict__ O) {
    int g = blockIdx.x * 256 + threadIdx.x;
    int q = g >> 4, seg = g & 15;
    float inv = 1.f / (Ml[q] + Ml[BHS + q]);
    f32x4 x = *(const f32x4*)(Op0 + (size_t)q * 64 + seg * 4);
    f32x4 y = *(const f32x4*)(Op1 + (size_t)q * 64 + seg * 4);
    int bh = q >> 11, sq = q & 2047, bb = bh >> 4, h = bh & 15;
    uint2 u;
    u.x = pk2((x[0] + y[0]) * inv, (x[1] + y[1]) * inv);
    u.y = pk2((x[2] + y[2]) * inv, (x[3] + y[3]) * inv);
    *(uint2*)(O + ((size_t)(bb * Ss + sq)) * Dd + h * 64 + seg * 4) = u;
}

// ---------------------------------------------------------------------------
// LayerNorm over D=1024 with up to 4 fp32 partial inputs (split-K GEMM slices)
__global__ __launch_bounds__(256) void ln_kernel(const float* __restrict__ a0,
                                                 const float* __restrict__ a1,
                                                 const float* __restrict__ a2,
                                                 const float* __restrict__ a3,
                                                 const float* __restrict__ resid,
                                                 const float* __restrict__ g,
                                                 const float* __restrict__ bt,
                                                 float* __restrict__ out32,
                                                 ushort* __restrict__ outb) {
    const int row = blockIdx.x, tid = threadIdx.x;
    const size_t base = (size_t)row * Dd + tid * 4;
    float4 av = *(const float4*)(a0 + base);
    if (a1) { float4 t = *(const float4*)(a1 + base); av.x += t.x; av.y += t.y; av.z += t.z; av.w += t.w; }
    if (a2) { float4 t = *(const float4*)(a2 + base); av.x += t.x; av.y += t.y; av.z += t.z; av.w += t.w; }
    if (a3) { float4 t = *(const float4*)(a3 + base); av.x += t.x; av.y += t.y; av.z += t.z; av.w += t.w; }
    float4 rv = *(const float4*)(resid + base);
    float x0 = av.x + rv.x, x1 = av.y + rv.y, x2 = av.z + rv.z, x3 = av.w + rv.w;
    float s = x0 + x1 + x2 + x3;
    float q = x0 * x0 + x1 * x1 + x2 * x2 + x3 * x3;
#pragma unroll
    for (int off = 1; off <= 32; off <<= 1) {
        s += __shfl_xor(s, off);
        q += __shfl_xor(q, off);
    }
    __shared__ float red[8];
    int wave = tid >> 6, lane = tid & 63;
    if (lane == 0) { red[wave] = s; red[4 + wave] = q; }
    __syncthreads();
    s = red[0] + red[1] + red[2] + red[3];
    q = red[4] + red[5] + red[6] + red[7];
    float mu = s * (1.f / Dd);
    float var = q * (1.f / Dd) - mu * mu;
    float rs = rsqrtf(var + 1e-5f);
    int col = tid * 4;
    float4 gv = *(const float4*)(g + col);
    float4 bv = *(const float4*)(bt + col);
    float y0 = (x0 - mu) * rs * gv.x + bv.x;
    float y1 = (x1 - mu) * rs * gv.y + bv.y;
    float y2 = (x2 - mu) * rs * gv.z + bv.z;
    float y3 = (x3 - mu) * rs * gv.w + bv.w;
    if (out32) *(float4*)(out32 + base) = make_float4(y0, y1, y2, y3);
    if (outb) {
        ushort4 u; u.x = f2b(y0); u.y = f2b(y1); u.z = f2b(y2); u.w = f2b(y3);
        *(ushort4*)(outb + base) = u;
    }
}

// ---------------------------------------------------------------------------
// workspace layout (bytes)
constexpr size_t OFF_XB     = 0;
constexpr size_t OFF_ENCB   = OFF_XB     + 8388608;
constexpr size_t OFF_QKVWT  = OFF_ENCB   + 8388608;
constexpr size_t OFF_CAWQT  = OFF_QKVWT  + 6291456;
constexpr size_t OFF_CAKVT  = OFF_CAWQT  + 2097152;
constexpr size_t OFF_SAWOT  = OFF_CAKVT  + 4194304;
constexpr size_t OFF_CAWOT  = OFF_SAWOT  + 2097152;
constexpr size_t OFF_FW1T   = OFF_CAWOT  + 2097152;
constexpr size_t OFF_FW2T   = OFF_FW1T   + 8388608;
constexpr size_t OFF_SABQKV = OFF_FW2T   + 8388608;
constexpr size_t OFF_CABKV  = OFF_SABQKV + 12288;
constexpr size_t OFF_QB     = OFF_CABKV  + 8192;      // 25.2MB qkv; later y_fp32 scratch
constexpr size_t OFF_KB     = OFF_QB     + 8388608;
constexpr size_t OFF_VB     = OFF_KB     + 8388608;   // holds V^T
constexpr size_t OFF_ATTNO  = OFF_VB     + 8388608;
constexpr size_t OFF_F1     = OFF_ATTNO  + 8388608;   // 16MiB fp32 slice 0
constexpr size_t OFF_F2     = OFF_F1     + 16777216;  // slice 1
constexpr size_t OFF_X1B    = OFF_F2     + 16777216;  // bf16 x1; part of slice 2
constexpr size_t OFF_F3     = OFF_X1B    + 8388608;   // x1 fp32 / slice 2-3 span
constexpr size_t OFF_YB     = OFF_F3     + 16777216;  // bf16 y; part of slice 3
constexpr size_t OFF_H1B    = OFF_YB     + 8388608;   // FFN hidden; Ml scratch during attn
// F1..H1B span = 16+16+8+16+8 MiB = 64 MiB = exactly 4 fp32 M*N slices.

extern "C" void kernel_launch(void* const* d_in, const int* in_sizes, int n_in,
                              void* d_out, int out_size, void* d_ws, size_t ws_size,
                              hipStream_t stream) {
    const float* enc   = (const float*)d_in[0];
    const float* dec   = (const float*)d_in[1];
    const float* sa_wq = (const float*)d_in[2];
    const float* sa_bq = (const float*)d_in[3];
    const float* sa_wk = (const float*)d_in[4];
    const float* sa_bk = (const float*)d_in[5];
    const float* sa_wv = (const float*)d_in[6];
    const float* sa_bv = (const float*)d_in[7];
    const float* sa_wo = (const float*)d_in[8];
    const float* sa_bo = (const float*)d_in[9];
    const float* sa_g  = (const float*)d_in[10];
    const float* sa_bt = (const float*)d_in[11];
    const float* ca_wq = (const float*)d_in[12];
    const float* ca_bq = (const float*)d_in[13];
    const float* ca_wk = (const float*)d_in[14];
    const float* ca_bk = (const float*)d_in[15];
    const float* ca_wv = (const float*)d_in[16];
    const float* ca_bv = (const float*)d_in[17];
    const float* ca_wo = (const float*)d_in[18];
    const float* ca_bo = (const float*)d_in[19];
    const float* ca_g  = (const float*)d_in[20];
    const float* ca_bt = (const float*)d_in[21];
    const float* f_w1  = (const float*)d_in[22];
    const float* f_b1  = (const float*)d_in[23];
    const float* f_w2  = (const float*)d_in[24];
    const float* f_b2  = (const float*)d_in[25];
    const float* f_g   = (const float*)d_in[26];
    const float* f_bt  = (const float*)d_in[27];

    char* ws = (char*)d_ws;
    ushort* xb     = (ushort*)(ws + OFF_XB);
    ushort* encb   = (ushort*)(ws + OFF_ENCB);
    ushort* qkvwT  = (ushort*)(ws + OFF_QKVWT);
    ushort* cawqT  = (ushort*)(ws + OFF_CAWQT);
    ushort* cakvT  = (ushort*)(ws + OFF_CAKVT);
    ushort* sawoT  = (ushort*)(ws + OFF_SAWOT);
    ushort* cawoT  = (ushort*)(ws + OFF_CAWOT);
    ushort* fw1T   = (ushort*)(ws + OFF_FW1T);
    ushort* fw2T   = (ushort*)(ws + OFF_FW2T);
    float*  sabqkv = (float*)(ws + OFF_SABQKV);
    float*  cabkv  = (float*)(ws + OFF_CABKV);
    ushort* qb     = (ushort*)(ws + OFF_QB);
    ushort* kb     = (ushort*)(ws + OFF_KB);
    ushort* vbt    = (ushort*)(ws + OFF_VB);
    ushort* attno  = (ushort*)(ws + OFF_ATTNO);
    float*  f1     = (float*)(ws + OFF_F1);     // split slice 0 / attn Op0
    float*  f2     = (float*)(ws + OFF_F2);     // split slice 1 / attn Op1 (CA)
    ushort* x1b    = (ushort*)(ws + OFF_X1B);
    float*  x1f    = (float*)(ws + OFF_F3);     // x fp32 (SA-LN out, CA resid)
    ushort* yb     = (ushort*)(ws + OFF_YB);
    ushort* h1b    = (ushort*)(ws + OFF_H1B);
    float*  yfp    = (float*)(ws + OFF_QB);     // y fp32 (CA-LN out, FFN resid)
    float*  ml     = (float*)(ws + OFF_H1B);    // 512 KB, dead during attention

    const float QSC = 0.125f * LOG2E;
    const size_t MN = (size_t)Mrows * Dd;       // 4M elems = 16 MiB fp32

    // ---- pre-pass ----
    cvt_kernel<<<4096, 256, 0, stream>>>(dec, xb);
    cvt_kernel<<<4096, 256, 0, stream>>>(enc, encb);
    dim3 tgDD(32, 32);
    wtrans_kernel<<<tgDD, 256, 0, stream>>>(sa_wq, qkvwT,                 Dd, Dd);
    wtrans_kernel<<<tgDD, 256, 0, stream>>>(sa_wk, qkvwT + 1024 * 1024,   Dd, Dd);
    wtrans_kernel<<<tgDD, 256, 0, stream>>>(sa_wv, qkvwT + 2 * 1024 * 1024, Dd, Dd);
    wtrans_kernel<<<tgDD, 256, 0, stream>>>(sa_wo, sawoT,                 Dd, Dd);
    wtrans_kernel<<<tgDD, 256, 0, stream>>>(ca_wq, cawqT,                 Dd, Dd);
    wtrans_kernel<<<tgDD, 256, 0, stream>>>(ca_wk, cakvT,                 Dd, Dd);
    wtrans_kernel<<<tgDD, 256, 0, stream>>>(ca_wv, cakvT + 1024 * 1024,   Dd, Dd);
    wtrans_kernel<<<tgDD, 256, 0, stream>>>(ca_wo, cawoT,                 Dd, Dd);
    wtrans_kernel<<<dim3(128, 32), 256, 0, stream>>>(f_w1, fw1T, Dd, Ff);
    wtrans_kernel<<<dim3(32, 128), 256, 0, stream>>>(f_w2, fw2T, Ff, Dd);
    pack_bias<<<12, 256, 0, stream>>>(sa_bq, sa_bk, sa_bv, sabqkv);
    pack_bias<<<8, 256, 0, stream>>>(ca_bk, ca_bv, nullptr, cabkv);

    // ---- self-attention ----
    gemm_kernel<<<dim3(24, 32, 1), 256, 0, stream>>>(xb, qkvwT, sabqkv, qb,
                                                     Mrows, 3072, Dd, Dd, 2, 0, QSC, 2);
    attn_kernel<<<dim3(16, 32, 2), 256, 0, stream>>>(qb, kb, vbt, f1, x1f, ml, 1);
    attn_combine<<<4096, 256, 0, stream>>>(f1, x1f, ml, attno);
    // O-proj split-K x2 -> slices f1, f2
    gemm_kernel<<<dim3(8, 32, 2), 256, 0, stream>>>(attno, sawoT, sa_bo, f1,
                                                    Mrows, Dd, Dd, 512, 0, 0, 1.f, -1);
    ln_kernel<<<4096, 256, 0, stream>>>(f1, f2, nullptr, nullptr, dec,
                                        sa_g, sa_bt, x1f, x1b);

    // ---- cross-attention ----
    gemm_kernel<<<dim3(8, 32, 1), 256, 0, stream>>>(x1b, cawqT, ca_bq, qb,
                                                    Mrows, Dd, Dd, Dd, 2, 0, QSC, -1);
    gemm_kernel<<<dim3(16, 32, 1), 256, 0, stream>>>(encb, cakvT, cabkv, kb,
                                                     Mrows, 2048, Dd, Dd, 2, 0, 1.f, 1);
    attn_kernel<<<dim3(16, 32, 2), 256, 0, stream>>>(qb, kb, vbt, f1, f2, ml, 0);
    attn_combine<<<4096, 256, 0, stream>>>(f1, f2, ml, attno);
    gemm_kernel<<<dim3(8, 32, 2), 256, 0, stream>>>(attno, cawoT, ca_bo, f1,
                                                    Mrows, Dd, Dd, 512, 0, 0, 1.f, -1);
    ln_kernel<<<4096, 256, 0, stream>>>(f1, f2, nullptr, nullptr, x1f,
                                        ca_g, ca_bt, yfp, yb);

    // ---- FFN ----
    gemm_kernel<<<dim3(32, 32, 1), 256, 0, stream>>>(yb, fw1T, f_b1, h1b,
                                                     Mrows, Ff, Dd, Dd, 1, 1, 1.f, -1);
    // FFN2 split-K x4 -> slices f1..f1+3*MN (span ends exactly at OFF_H1B)
    gemm_kernel<<<dim3(8, 32, 4), 256, 0, stream>>>(h1b, fw2T, f_b2, f1,
                                                    Mrows, Dd, Ff, 1024, 0, 0, 1.f, -1);
    ln_kernel<<<4096, 256, 0, stream>>>(f1, f1 + MN, f1 + 2 * MN, f1 + 3 * MN, yfp,
                                        f_g, f_bt, (float*)d_out, nullptr);
}